// Round 14
// baseline (349.957 us; speedup 1.0000x reference)
//
#include <hip/hip_runtime.h>
#include <math.h>

#define BB 32
#define TT 512
#define EE 128
#define NHH 16
#define HDD 8
#define G3 384
#define NGRU 96
#define NATT 192

typedef __attribute__((ext_vector_type(2))) _Float16 half2_t;
typedef __attribute__((ext_vector_type(8))) _Float16 half8_t;

__device__ __forceinline__ float exp2_(float x) {
#if __has_builtin(__builtin_amdgcn_exp2f)
  return __builtin_amdgcn_exp2f(x);
#else
  return exp2f(x);
#endif
}

__device__ __forceinline__ float fdot2_(half2_t a, half2_t b, float c) {
#if __has_builtin(__builtin_amdgcn_fdot2)
  return __builtin_amdgcn_fdot2(a, b, c, false);
#else
  return fmaf((float)a[0], (float)b[0], fmaf((float)a[1], (float)b[1], c));
#endif
}

// DPP quad-perm adds: xor1 = [1,0,3,2] = 0xB1, xor2 = [2,3,0,1] = 0x4E.
__device__ __forceinline__ float qp_add1(float x) {
  int t = __builtin_amdgcn_update_dpp(0, __float_as_int(x), 0xB1, 0xF, 0xF, true);
  return x + __int_as_float(t);
}
__device__ __forceinline__ float qp_add2(float x) {
  int t = __builtin_amdgcn_update_dpp(0, __float_as_int(x), 0x4E, 0xF, 0xF, true);
  return x + __int_as_float(t);
}

// K0: fold lookup/posres/attn_in into coef[5][384] and per-head 5x5 M (scaled).
__global__ __launch_bounds__(512) void coef_kernel(
    const float* __restrict__ attn_in_w, const float* __restrict__ attn_in_b,
    const float* __restrict__ lookup_w, const float* __restrict__ lookup_b,
    const float* __restrict__ posres_w, const float* __restrict__ posres_b,
    float* __restrict__ coef, float* __restrict__ Mh) {
  int j = threadIdx.x;
  __shared__ float cL[5][G3];
  if (j < G3) {
    float u0 = 0.f, u1 = 0.f, cs = 0.f, cc = 0.f, cb = 0.f;
    const float* wrow = attn_in_w + j * EE;
    for (int e = 0; e < EE; ++e) {
      float w = wrow[e];
      float pw0 = posres_w[e * 2], pw1 = posres_w[e * 2 + 1];
      u0 += w * (lookup_w[e * 2] + pw0);
      u1 += w * (lookup_w[e * 2 + 1] + pw1);
      cs += w * pw0;
      cc += w * pw1;
      cb += w * (lookup_b[e] + posres_b[e]);
    }
    cb += attn_in_b[j];
    coef[0 * G3 + j] = u0;
    coef[1 * G3 + j] = u1;
    coef[2 * G3 + j] = cs;
    coef[3 * G3 + j] = cc;
    coef[4 * G3 + j] = cb;
    cL[0][j] = u0;
    cL[1][j] = u1;
    cL[2][j] = cs;
    cL[3][j] = cc;
    cL[4][j] = cb;
  }
  __syncthreads();
  if (j < NHH * 25) {
    int h = j / 25;
    int ij = j % 25;
    int i = ij / 5, jj = ij % 5;
    const float SCL = 0.35355339059327373f * 1.4426950408889634f;
    float acc = 0.f;
#pragma unroll
    for (int d = 0; d < HDD; ++d)
      acc += cL[i][h * HDD + d] * cL[jj][EE + h * HDD + d];
    Mh[h * 25 + ij] = acc * SCL;
  }
}

// Merged kernel: blocks [0,96) = GRU (one per (s,b), 512 thr, 4-lane groups);
// blocks [96,96+192) = attention (wave = head).
__global__ __launch_bounds__(512, 1) void fused_kernel(
    const float* __restrict__ in0, const float* __restrict__ in1,
    const float* __restrict__ in2, const int* __restrict__ len0,
    const int* __restrict__ len1, const int* __restrict__ len2,
    const float* __restrict__ w_ih, const float* __restrict__ w_hh,
    const float* __restrict__ b_ih, const float* __restrict__ b_hh,
    const float* __restrict__ coef, const float* __restrict__ Mh,
    float* __restrict__ coor_embs, float* __restrict__ ohat) {
  __shared__ __align__(16) unsigned char smem[8192];
  int tid = threadIdx.x;
  if (blockIdx.x < NGRU) {
    // ---------------- GRU: 4-lane groups, DPP reduce, high wave priority -----
    __builtin_amdgcn_s_setprio(1);
    const float L2E = 1.4426950408889634f;
    const float L2E2 = 2.8853900817779268f;
    int blk = blockIdx.x;
    int s = blk >> 5;
    int b = blk & 31;
    const float* inp = (s == 0) ? in0 : (s == 1) ? in1 : in2;
    const int* lenp = (s == 0) ? len0 : (s == 1) ? len1 : len2;
    int len = lenp[b];
    int e = tid >> 2;   // h element / gate-triple index 0..127
    int kp = tid & 3;   // k-slice 0..3 (32 cols each)

    _Float16* hbh = (_Float16*)smem;          // [2][128]
    float* xst = (float*)(smem + 512);        // [512][2]

    {
      float4 v = *(const float4*)(inp + ((size_t)b * TT + tid) * 4);
      xst[tid * 2] = v.x;
      xst[tid * 2 + 1] = v.y;
    }
    if (tid < EE) hbh[tid] = (_Float16)0.0f;

    int rr = e, rz = e + 128, rn = e + 256;
    // pack 32-col slices, folding log2e (r,z) / 2*log2e (n) into the weights
    half2_t wr[16], wz[16], wn[16];
    {
      const float4* pr = (const float4*)(w_hh + (size_t)rr * EE + 32 * kp);
      const float4* pz = (const float4*)(w_hh + (size_t)rz * EE + 32 * kp);
      const float4* pn = (const float4*)(w_hh + (size_t)rn * EE + 32 * kp);
#pragma unroll
      for (int i = 0; i < 8; ++i) {
        float4 a = pr[i];
        wr[2 * i][0] = (_Float16)(a.x * L2E); wr[2 * i][1] = (_Float16)(a.y * L2E);
        wr[2 * i + 1][0] = (_Float16)(a.z * L2E); wr[2 * i + 1][1] = (_Float16)(a.w * L2E);
        float4 c = pz[i];
        wz[2 * i][0] = (_Float16)(c.x * L2E); wz[2 * i][1] = (_Float16)(c.y * L2E);
        wz[2 * i + 1][0] = (_Float16)(c.z * L2E); wz[2 * i + 1][1] = (_Float16)(c.w * L2E);
        float4 d = pn[i];
        wn[2 * i][0] = (_Float16)(d.x * L2E2); wn[2 * i][1] = (_Float16)(d.y * L2E2);
        wn[2 * i + 1][0] = (_Float16)(d.z * L2E2); wn[2 * i + 1][1] = (_Float16)(d.w * L2E2);
      }
    }
    float br = (b_ih[rr] + b_hh[rr]) * L2E;
    float bz = (b_ih[rz] + b_hh[rz]) * L2E;
    float bn = b_ih[rn] * L2E2;
    float bhn = b_hh[rn] * L2E2;
    float wir0 = w_ih[rr * 2] * L2E, wir1 = w_ih[rr * 2 + 1] * L2E;
    float wiz0 = w_ih[rz * 2] * L2E, wiz1 = w_ih[rz * 2 + 1] * L2E;
    float win0 = w_ih[rn * 2] * L2E2, win1 = w_ih[rn * 2 + 1] * L2E2;

    float hold = 0.0f;
    __syncthreads();

    int cur = 0;
#pragma unroll 1
    for (int t = 0; t < len; ++t) {
      // 32 h-halfs via 4 broadcast b128 reads (16 lanes/addr: free)
      const half8_t* hp = (const half8_t*)(hbh + cur * EE + 32 * kp);
      half8_t H0 = hp[0], H1 = hp[1], H2 = hp[2], H3 = hp[3];
      const half2_t* c0 = (const half2_t*)&H0;
      const half2_t* c1 = (const half2_t*)&H1;
      const half2_t* c2 = (const half2_t*)&H2;
      const half2_t* c3 = (const half2_t*)&H3;
      float x0 = xst[t * 2], x1 = xst[t * 2 + 1];

      float ar0 = 0.f, ar1 = 0.f, az0 = 0.f, az1 = 0.f, an0 = 0.f, an1 = 0.f;
#pragma unroll
      for (int jj = 0; jj < 4; ++jj) {
        ar0 = fdot2_(wr[jj], c0[jj], ar0);
        az0 = fdot2_(wz[jj], c0[jj], az0);
        an0 = fdot2_(wn[jj], c0[jj], an0);
        ar1 = fdot2_(wr[4 + jj], c1[jj], ar1);
        az1 = fdot2_(wz[4 + jj], c1[jj], az1);
        an1 = fdot2_(wn[4 + jj], c1[jj], an1);
        ar0 = fdot2_(wr[8 + jj], c2[jj], ar0);
        az0 = fdot2_(wz[8 + jj], c2[jj], az0);
        an0 = fdot2_(wn[8 + jj], c2[jj], an0);
        ar1 = fdot2_(wr[12 + jj], c3[jj], ar1);
        az1 = fdot2_(wz[12 + jj], c3[jj], az1);
        an1 = fdot2_(wn[12 + jj], c3[jj], an1);
      }
      float hr = ar0 + ar1, hz = az0 + az1, hn = an0 + an1;

      // 4-lane group reduce via DPP quad-perm (pure VALU, no LDS pipe)
      hr = qp_add1(hr);
      hz = qp_add1(hz);
      hn = qp_add1(hn);
      hr = qp_add2(hr);
      hz = qp_add2(hz);
      hn = qp_add2(hn);

      // exp2-native gates (log2e pre-folded)
      float r = __builtin_amdgcn_rcpf(1.0f + exp2_(-(br + wir0 * x0 + wir1 * x1 + hr)));
      float z = __builtin_amdgcn_rcpf(1.0f + exp2_(-(bz + wiz0 * x0 + wiz1 * x1 + hz)));
      float targ2 = bn + win0 * x0 + win1 * x1 + r * (bhn + hn);  // = 2*log2e*targ
      float n = 1.0f - 2.0f * __builtin_amdgcn_rcpf(exp2_(targ2) + 1.0f);  // tanh
      hold = n + z * (hold - n);
      if (kp == 0) hbh[(cur ^ 1) * EE + e] = (_Float16)hold;
      __syncthreads();
      cur ^= 1;
    }
    __builtin_amdgcn_s_setprio(0);
    if (kp == 0) coor_embs[(size_t)blk * EE + e] = hold;
  } else {
    // ---------------- Attention (rank-5, q-register-tiled, wave=head) --------
    int a = blockIdx.x - NGRU;  // 0..191: (s, b, head-group)
    int s = a / 64;
    int rem = a - s * 64;
    int b = rem >> 1;
    int hg = rem & 1;
    const float* inp = (s == 0) ? in0 : (s == 1) ? in1 : in2;
    int wave = tid >> 6;
    int lane = tid & 63;
    int h = hg * 8 + wave;

    float4* phiL = (float4*)smem;  // [512]

    {
      int t = tid;
      float ft = (float)t;
      float st = sinf(ft);
      float ct = cosf(ft);
      float4 g = *(const float4*)(inp + ((size_t)b * TT + t) * 4);
      phiL[t] = make_float4(g.z, g.w, st, ct);
    }

    float M[25];
#pragma unroll
    for (int i = 0; i < 25; ++i) M[i] = Mh[h * 25 + i];
    __syncthreads();

    float4 p[8];
#pragma unroll
    for (int j = 0; j < 8; ++j) p[j] = phiL[lane + 64 * j];

    float Z[8];
    float N0[8], N1[8], N2[8], N3[8];
#pragma unroll
    for (int j = 0; j < 8; ++j) {
      Z[j] = 0.f; N0[j] = 0.f; N1[j] = 0.f; N2[j] = 0.f; N3[j] = 0.f;
    }

#pragma unroll 1
    for (int k = 0; k < TT; ++k) {
      float4 f = phiL[k];
      float m0 = fmaf(M[0], f.x, fmaf(M[1], f.y, fmaf(M[2], f.z, fmaf(M[3], f.w, M[4]))));
      float m1 = fmaf(M[5], f.x, fmaf(M[6], f.y, fmaf(M[7], f.z, fmaf(M[8], f.w, M[9]))));
      float m2 = fmaf(M[10], f.x, fmaf(M[11], f.y, fmaf(M[12], f.z, fmaf(M[13], f.w, M[14]))));
      float m3 = fmaf(M[15], f.x, fmaf(M[16], f.y, fmaf(M[17], f.z, fmaf(M[18], f.w, M[19]))));
      float m4 = fmaf(M[20], f.x, fmaf(M[21], f.y, fmaf(M[22], f.z, fmaf(M[23], f.w, M[24]))));
#pragma unroll
      for (int j = 0; j < 8; ++j) {
        float e0 = exp2_(fmaf(p[j].x, m0, fmaf(p[j].y, m1, fmaf(p[j].z, m2, fmaf(p[j].w, m3, m4)))));
        Z[j] += e0;
        N0[j] = fmaf(e0, f.x, N0[j]);
        N1[j] = fmaf(e0, f.y, N1[j]);
        N2[j] = fmaf(e0, f.z, N2[j]);
        N3[j] = fmaf(e0, f.w, N3[j]);
      }
    }

    float od0 = 0.f, od1 = 0.f, od2 = 0.f, od3 = 0.f;
#pragma unroll
    for (int j = 0; j < 8; ++j) {
      float rz = __builtin_amdgcn_rcpf(Z[j] * (float)TT);
      od0 = fmaf(N0[j], rz, od0);
      od1 = fmaf(N1[j], rz, od1);
      od2 = fmaf(N2[j], rz, od2);
      od3 = fmaf(N3[j], rz, od3);
    }
#pragma unroll
    for (int off = 32; off >= 1; off >>= 1) {
      od0 += __shfl_xor(od0, off, 64);
      od1 += __shfl_xor(od1, off, 64);
      od2 += __shfl_xor(od2, off, 64);
      od3 += __shfl_xor(od3, off, 64);
    }
    if (lane < HDD) {
      int jv = 2 * EE + h * HDD + lane;
      float o = coef[jv] * od0 + coef[G3 + jv] * od1 + coef[2 * G3 + jv] * od2 +
                coef[3 * G3 + jv] * od3 + coef[4 * G3 + jv];  // phi4 == 1 exactly
      int abk = s * 512 + b * 16 + h;
      ohat[(size_t)abk * HDD + lane] = o;
    }
  }
}

// K3: grid_emb = ohat @ out_w.T + out_b ; out = gamma*coor + (1-gamma)*grid
__global__ __launch_bounds__(128) void finalize_kernel(
    const float* __restrict__ attn_out_w, const float* __restrict__ attn_out_b,
    const float* __restrict__ ohat, const float* __restrict__ coor_embs,
    const float* __restrict__ gamma_p, float* __restrict__ out) {
  int blk = blockIdx.x;  // s*32 + b
  int e = threadIdx.x;
  __shared__ float ov[EE];
  ov[e] = ohat[(size_t)blk * EE + e];
  __syncthreads();
  float acc = attn_out_b[e];
  const float* wrow = attn_out_w + (size_t)e * EE;
#pragma unroll 8
  for (int f = 0; f < EE; ++f) acc += wrow[f] * ov[f];
  float g = gamma_p[0];
  out[(size_t)blk * EE + e] = g * coor_embs[(size_t)blk * EE + e] + (1.0f - g) * acc;
}

// K4: pos/neg distances from the embeddings already in d_out
__global__ void dist_kernel(float* __restrict__ out) {
  int i = threadIdx.x;  // 64 threads
  int b = i & 31;
  int neg = i >> 5;
  const float* a = out + (size_t)b * EE;
  const float* x = out + (size_t)(1 + neg) * BB * EE + (size_t)b * EE;
  float sum = 0.f;
  for (int e = 0; e < EE; ++e) {
    float d = a[e] - x[e] + 1e-6f;
    sum += d * d;
  }
  out[3 * BB * EE + neg * BB + b] = expf(-sqrtf(sum));
}

extern "C" void kernel_launch(void* const* d_in, const int* in_sizes, int n_in,
                              void* d_out, int out_size, void* d_ws, size_t ws_size,
                              hipStream_t stream) {
  const float* a_in = (const float*)d_in[0];
  const float* p_in = (const float*)d_in[1];
  const float* ng_in = (const float*)d_in[2];
  const int* a_len = (const int*)d_in[3];
  const int* p_len = (const int*)d_in[4];
  const int* ng_len = (const int*)d_in[5];
  const float* w_ih = (const float*)d_in[6];
  const float* w_hh = (const float*)d_in[7];
  const float* b_ih = (const float*)d_in[8];
  const float* b_hh = (const float*)d_in[9];
  const float* lookup_w = (const float*)d_in[10];
  const float* lookup_b = (const float*)d_in[11];
  const float* posres_w = (const float*)d_in[12];
  const float* posres_b = (const float*)d_in[13];
  const float* attn_in_w = (const float*)d_in[14];
  const float* attn_in_b = (const float*)d_in[15];
  const float* attn_out_w = (const float*)d_in[16];
  const float* attn_out_b = (const float*)d_in[17];
  const float* gamma_p = (const float*)d_in[18];
  float* out = (float*)d_out;

  float* coef = (float*)d_ws;      // 5*384 = 1920 floats (pad to 2048)
  float* Mh = coef + 2048;         // 16*25 = 400 floats (pad to 512)
  float* ohat = Mh + 512;          // 3*32*16*8 = 12288 floats
  float* cemb = ohat + 12288;      // 3*32*128  = 12288 floats

  hipLaunchKernelGGL(coef_kernel, dim3(1), dim3(512), 0, stream, attn_in_w,
                     attn_in_b, lookup_w, lookup_b, posres_w, posres_b, coef, Mh);
  hipLaunchKernelGGL(fused_kernel, dim3(NGRU + NATT), dim3(512), 0, stream, a_in,
                     p_in, ng_in, a_len, p_len, ng_len, w_ih, w_hh, b_ih, b_hh,
                     coef, Mh, cemb, ohat);
  hipLaunchKernelGGL(finalize_kernel, dim3(96), dim3(128), 0, stream, attn_out_w,
                     attn_out_b, ohat, cemb, gamma_p, out);
  hipLaunchKernelGGL(dist_kernel, dim3(1), dim3(64), 0, stream, out);
}

// Round 15
// 292.564 us; speedup vs baseline: 1.1962x; 1.1962x over previous
//
#include <hip/hip_runtime.h>
#include <math.h>

#define BB 32
#define TT 512
#define EE 128
#define NHH 16
#define HDD 8
#define G3 384
#define NGRU 96
#define NATT 1536

typedef __attribute__((ext_vector_type(2))) _Float16 half2_t;
typedef __attribute__((ext_vector_type(8))) _Float16 half8_t;

__device__ __forceinline__ float sigmoidf_(float x) {
  return __builtin_amdgcn_rcpf(1.0f + __expf(-x));
}

__device__ __forceinline__ float exp2_(float x) {
#if __has_builtin(__builtin_amdgcn_exp2f)
  return __builtin_amdgcn_exp2f(x);
#else
  return exp2f(x);
#endif
}

__device__ __forceinline__ float fdot2_(half2_t a, half2_t b, float c) {
#if __has_builtin(__builtin_amdgcn_fdot2)
  return __builtin_amdgcn_fdot2(a, b, c, false);
#else
  return fmaf((float)a[0], (float)b[0], fmaf((float)a[1], (float)b[1], c));
#endif
}

#define SC5(p, m, n) \
  fmaf((p).x, (m).x, fmaf((p).y, (m).y, fmaf((p).z, (m).z, fmaf((p).w, (m).w, (n)))))

// K0: fold lookup/posres/attn_in into coef[5][384] and per-head 5x5 M (scaled).
__global__ __launch_bounds__(512) void coef_kernel(
    const float* __restrict__ attn_in_w, const float* __restrict__ attn_in_b,
    const float* __restrict__ lookup_w, const float* __restrict__ lookup_b,
    const float* __restrict__ posres_w, const float* __restrict__ posres_b,
    float* __restrict__ coef, float* __restrict__ Mh) {
  int j = threadIdx.x;
  __shared__ float cL[5][G3];
  if (j < G3) {
    float u0 = 0.f, u1 = 0.f, cs = 0.f, cc = 0.f, cb = 0.f;
    const float* wrow = attn_in_w + j * EE;
    for (int e = 0; e < EE; ++e) {
      float w = wrow[e];
      float pw0 = posres_w[e * 2], pw1 = posres_w[e * 2 + 1];
      u0 += w * (lookup_w[e * 2] + pw0);
      u1 += w * (lookup_w[e * 2 + 1] + pw1);
      cs += w * pw0;
      cc += w * pw1;
      cb += w * (lookup_b[e] + posres_b[e]);
    }
    cb += attn_in_b[j];
    coef[0 * G3 + j] = u0;
    coef[1 * G3 + j] = u1;
    coef[2 * G3 + j] = cs;
    coef[3 * G3 + j] = cc;
    coef[4 * G3 + j] = cb;
    cL[0][j] = u0;
    cL[1][j] = u1;
    cL[2][j] = cs;
    cL[3][j] = cc;
    cL[4][j] = cb;
  }
  __syncthreads();
  if (j < NHH * 25) {
    int h = j / 25;
    int ij = j % 25;
    int i = ij / 5, jj = ij % 5;
    const float SCL = 0.35355339059327373f * 1.4426950408889634f;
    float acc = 0.f;
#pragma unroll
    for (int d = 0; d < HDD; ++d)
      acc += cL[i][h * HDD + d] * cL[jj][EE + h * HDD + d];
    Mh[h * 25 + ij] = acc * SCL;
  }
}

// Merged hetero kernel: blocks [0,96) = GRU (one per (s,b));
// blocks [96, 96+1536) = attention (one per (s,b,head)).
__global__ __launch_bounds__(512) void fused_kernel(
    const float* __restrict__ in0, const float* __restrict__ in1,
    const float* __restrict__ in2, const int* __restrict__ len0,
    const int* __restrict__ len1, const int* __restrict__ len2,
    const float* __restrict__ w_ih, const float* __restrict__ w_hh,
    const float* __restrict__ b_ih, const float* __restrict__ b_hh,
    const float* __restrict__ coef, const float* __restrict__ Mh,
    float* __restrict__ coor_embs, float* __restrict__ ohat) {
  int tid = threadIdx.x;
  if (blockIdx.x < NGRU) {
    // ---------------- GRU ----------------
    int blk = blockIdx.x;
    int s = blk >> 5;
    int b = blk & 31;
    const float* inp = (s == 0) ? in0 : (s == 1) ? in1 : in2;
    const int* lenp = (s == 0) ? len0 : (s == 1) ? len1 : len2;
    int len = lenp[b];
    int e = tid >> 2;   // gate-row triple index 0..127
    int kp = tid & 3;   // k-slice 0..3 (32 cols each)

    __shared__ __align__(16) _Float16 hbh[2][EE];
    __shared__ __align__(16) float xst[TT * 2];

    {
      float4 v = *(const float4*)(inp + ((size_t)b * TT + tid) * 4);
      xst[tid * 2] = v.x;
      xst[tid * 2 + 1] = v.y;
    }
    if (tid < EE) hbh[0][tid] = (_Float16)0.0f;

    int rr = e, rz = e + 128, rn = e + 256;
    half2_t wr[16], wz[16], wn[16];
    {
      const float4* pr = (const float4*)(w_hh + (size_t)rr * EE + 32 * kp);
      const float4* pz = (const float4*)(w_hh + (size_t)rz * EE + 32 * kp);
      const float4* pn = (const float4*)(w_hh + (size_t)rn * EE + 32 * kp);
#pragma unroll
      for (int i = 0; i < 8; ++i) {
        float4 a = pr[i];
        wr[2 * i][0] = (_Float16)a.x; wr[2 * i][1] = (_Float16)a.y;
        wr[2 * i + 1][0] = (_Float16)a.z; wr[2 * i + 1][1] = (_Float16)a.w;
        float4 c = pz[i];
        wz[2 * i][0] = (_Float16)c.x; wz[2 * i][1] = (_Float16)c.y;
        wz[2 * i + 1][0] = (_Float16)c.z; wz[2 * i + 1][1] = (_Float16)c.w;
        float4 d = pn[i];
        wn[2 * i][0] = (_Float16)d.x; wn[2 * i][1] = (_Float16)d.y;
        wn[2 * i + 1][0] = (_Float16)d.z; wn[2 * i + 1][1] = (_Float16)d.w;
      }
    }
    float br = b_ih[rr] + b_hh[rr];
    float bz = b_ih[rz] + b_hh[rz];
    float bn = b_ih[rn];
    float bhn = b_hh[rn];
    float wir0 = w_ih[rr * 2], wir1 = w_ih[rr * 2 + 1];
    float wiz0 = w_ih[rz * 2], wiz1 = w_ih[rz * 2 + 1];
    float win0 = w_ih[rn * 2], win1 = w_ih[rn * 2 + 1];

    float hold = 0.0f;
    __syncthreads();

#pragma unroll 1
    for (int t = 0; t < len; ++t) {
      const half8_t* hp = (const half8_t*)(hbh[t & 1] + 32 * kp);
      half8_t H0 = hp[0], H1 = hp[1], H2 = hp[2], H3 = hp[3];
      half2_t h2[16];
#pragma unroll
      for (int m = 0; m < 4; ++m) {
        h2[m][0] = H0[2 * m]; h2[m][1] = H0[2 * m + 1];
        h2[4 + m][0] = H1[2 * m]; h2[4 + m][1] = H1[2 * m + 1];
        h2[8 + m][0] = H2[2 * m]; h2[8 + m][1] = H2[2 * m + 1];
        h2[12 + m][0] = H3[2 * m]; h2[12 + m][1] = H3[2 * m + 1];
      }
      float x0 = xst[t * 2], x1 = xst[t * 2 + 1];

      float ar0 = 0.f, ar1 = 0.f, az0 = 0.f, az1 = 0.f, an0 = 0.f, an1 = 0.f;
#pragma unroll
      for (int jj = 0; jj < 16; jj += 2) {
        ar0 = fdot2_(wr[jj], h2[jj], ar0);
        ar1 = fdot2_(wr[jj + 1], h2[jj + 1], ar1);
        az0 = fdot2_(wz[jj], h2[jj], az0);
        az1 = fdot2_(wz[jj + 1], h2[jj + 1], az1);
        an0 = fdot2_(wn[jj], h2[jj], an0);
        an1 = fdot2_(wn[jj + 1], h2[jj + 1], an1);
      }
      float hr = ar0 + ar1, hz = az0 + az1, hn = an0 + an1;

      hr += __shfl_xor(hr, 1);
      hz += __shfl_xor(hz, 1);
      hn += __shfl_xor(hn, 1);
      hr += __shfl_xor(hr, 2);
      hz += __shfl_xor(hz, 2);
      hn += __shfl_xor(hn, 2);

      float r = sigmoidf_(br + wir0 * x0 + wir1 * x1 + hr);
      float z = sigmoidf_(bz + wiz0 * x0 + wiz1 * x1 + hz);
      float targ = bn + win0 * x0 + win1 * x1 + r * (bhn + hn);
      float ex = __expf(2.0f * targ);
      float n = 1.0f - 2.0f * __builtin_amdgcn_rcpf(ex + 1.0f);  // tanh
      hold = n + z * (hold - n);
      if (kp == 0) hbh[(t & 1) ^ 1][e] = (_Float16)hold;
      __syncthreads();
    }
    if (kp == 0) coor_embs[(size_t)blk * EE + e] = hold;
  } else {
    // ---------------- Attention (rank-5, single pass) ----------------
    int abk = blockIdx.x - NGRU;  // s*512 + b*16 + h
    int s = abk >> 9;
    int bh = abk & 511;
    int b = bh >> 4;
    int h = bh & 15;
    const float* inp = (s == 0) ? in0 : (s == 1) ? in1 : in2;

    __shared__ __align__(16) float4 phiL[TT];
    __shared__ __align__(16) float4 mk4L[TT];
    __shared__ float mk1L[TT];
    __shared__ float red[8][4];

    float M[25];
#pragma unroll
    for (int i = 0; i < 25; ++i) M[i] = Mh[h * 25 + i];

    {
      int t = tid;
      float ft = (float)t;
      float st = sinf(ft);
      float ct = cosf(ft);
      float4 g = *(const float4*)(inp + ((size_t)b * TT + t) * 4);
      float4 phi = make_float4(g.z, g.w, st, ct);
      phiL[t] = phi;
      float m0 = fmaf(M[0], phi.x, fmaf(M[1], phi.y, fmaf(M[2], phi.z, fmaf(M[3], phi.w, M[4]))));
      float m1 = fmaf(M[5], phi.x, fmaf(M[6], phi.y, fmaf(M[7], phi.z, fmaf(M[8], phi.w, M[9]))));
      float m2 = fmaf(M[10], phi.x, fmaf(M[11], phi.y, fmaf(M[12], phi.z, fmaf(M[13], phi.w, M[14]))));
      float m3 = fmaf(M[15], phi.x, fmaf(M[16], phi.y, fmaf(M[17], phi.z, fmaf(M[18], phi.w, M[19]))));
      float m4 = fmaf(M[20], phi.x, fmaf(M[21], phi.y, fmaf(M[22], phi.z, fmaf(M[23], phi.w, M[24]))));
      mk4L[t] = make_float4(m0, m1, m2, m3);
      mk1L[t] = m4;
    }
    __syncthreads();

    float od0, od1, od2, od3;
    {
      float4 p0 = phiL[tid];
      float Z0 = 0.f;
      float n00 = 0.f, n01 = 0.f, n02 = 0.f, n03 = 0.f;
#pragma unroll 2
      for (int k = 0; k < TT; ++k) {
        float4 m = mk4L[k];
        float n = mk1L[k];
        float4 f = phiL[k];
        float e0 = exp2_(SC5(p0, m, n));
        Z0 += e0;
        n00 = fmaf(e0, f.x, n00);
        n01 = fmaf(e0, f.y, n01);
        n02 = fmaf(e0, f.z, n02);
        n03 = fmaf(e0, f.w, n03);
      }
      float rz0 = 1.0f / (Z0 * (float)TT);
      od0 = n00 * rz0;
      od1 = n01 * rz0;
      od2 = n02 * rz0;
      od3 = n03 * rz0;
    }
#pragma unroll
    for (int off = 32; off >= 1; off >>= 1) {
      od0 += __shfl_xor(od0, off, 64);
      od1 += __shfl_xor(od1, off, 64);
      od2 += __shfl_xor(od2, off, 64);
      od3 += __shfl_xor(od3, off, 64);
    }
    {
      int wave = tid >> 6;
      int lane = tid & 63;
      if (lane == 0) {
        red[wave][0] = od0;
        red[wave][1] = od1;
        red[wave][2] = od2;
        red[wave][3] = od3;
      }
    }
    __syncthreads();
    if (tid < HDD) {
      float wp0 = 0.f, wp1 = 0.f, wp2 = 0.f, wp3 = 0.f;
#pragma unroll
      for (int w = 0; w < 8; ++w) {
        wp0 += red[w][0];
        wp1 += red[w][1];
        wp2 += red[w][2];
        wp3 += red[w][3];
      }
      int jv = 2 * EE + h * HDD + tid;
      float o = coef[jv] * wp0 + coef[G3 + jv] * wp1 + coef[2 * G3 + jv] * wp2 +
                coef[3 * G3 + jv] * wp3 + coef[4 * G3 + jv];  // phi4 == 1 exactly
      ohat[(size_t)abk * HDD + tid] = o;
    }
  }
}

// K3: grid_emb = ohat @ out_w.T + out_b ; out = gamma*coor + (1-gamma)*grid
__global__ __launch_bounds__(128) void finalize_kernel(
    const float* __restrict__ attn_out_w, const float* __restrict__ attn_out_b,
    const float* __restrict__ ohat, const float* __restrict__ coor_embs,
    const float* __restrict__ gamma_p, float* __restrict__ out) {
  int blk = blockIdx.x;  // s*32 + b
  int e = threadIdx.x;
  __shared__ float ov[EE];
  ov[e] = ohat[(size_t)blk * EE + e];
  __syncthreads();
  float acc = attn_out_b[e];
  const float* wrow = attn_out_w + (size_t)e * EE;
#pragma unroll 8
  for (int f = 0; f < EE; ++f) acc += wrow[f] * ov[f];
  float g = gamma_p[0];
  out[(size_t)blk * EE + e] = g * coor_embs[(size_t)blk * EE + e] + (1.0f - g) * acc;
}

// K4: pos/neg distances from the embeddings already in d_out
__global__ void dist_kernel(float* __restrict__ out) {
  int i = threadIdx.x;  // 64 threads
  int b = i & 31;
  int neg = i >> 5;
  const float* a = out + (size_t)b * EE;
  const float* x = out + (size_t)(1 + neg) * BB * EE + (size_t)b * EE;
  float sum = 0.f;
  for (int e = 0; e < EE; ++e) {
    float d = a[e] - x[e] + 1e-6f;
    sum += d * d;
  }
  out[3 * BB * EE + neg * BB + b] = expf(-sqrtf(sum));
}

extern "C" void kernel_launch(void* const* d_in, const int* in_sizes, int n_in,
                              void* d_out, int out_size, void* d_ws, size_t ws_size,
                              hipStream_t stream) {
  const float* a_in = (const float*)d_in[0];
  const float* p_in = (const float*)d_in[1];
  const float* ng_in = (const float*)d_in[2];
  const int* a_len = (const int*)d_in[3];
  const int* p_len = (const int*)d_in[4];
  const int* ng_len = (const int*)d_in[5];
  const float* w_ih = (const float*)d_in[6];
  const float* w_hh = (const float*)d_in[7];
  const float* b_ih = (const float*)d_in[8];
  const float* b_hh = (const float*)d_in[9];
  const float* lookup_w = (const float*)d_in[10];
  const float* lookup_b = (const float*)d_in[11];
  const float* posres_w = (const float*)d_in[12];
  const float* posres_b = (const float*)d_in[13];
  const float* attn_in_w = (const float*)d_in[14];
  const float* attn_in_b = (const float*)d_in[15];
  const float* attn_out_w = (const float*)d_in[16];
  const float* attn_out_b = (const float*)d_in[17];
  const float* gamma_p = (const float*)d_in[18];
  float* out = (float*)d_out;

  float* coef = (float*)d_ws;      // 5*384 = 1920 floats (pad to 2048)
  float* Mh = coef + 2048;         // 16*25 = 400 floats (pad to 512)
  float* ohat = Mh + 512;          // 3*32*16*8 = 12288 floats
  float* cemb = ohat + 12288;      // 3*32*128  = 12288 floats

  hipLaunchKernelGGL(coef_kernel, dim3(1), dim3(512), 0, stream, attn_in_w,
                     attn_in_b, lookup_w, lookup_b, posres_w, posres_b, coef, Mh);
  hipLaunchKernelGGL(fused_kernel, dim3(NGRU + NATT), dim3(512), 0, stream, a_in,
                     p_in, ng_in, a_len, p_len, ng_len, w_ih, w_hh, b_ih, b_hh,
                     coef, Mh, cemb, ohat);
  hipLaunchKernelGGL(finalize_kernel, dim3(96), dim3(128), 0, stream, attn_out_w,
                     attn_out_b, ohat, cemb, gamma_p, out);
  hipLaunchKernelGGL(dist_kernel, dim3(1), dim3(64), 0, stream, out);
}